// Round 1
// 15630.957 us; speedup vs baseline: 1.0263x; 1.0263x over previous
//
#include <hip/hip_runtime.h>
#include <hip/hip_bf16.h>
#include <math.h>

// MultiLayerRNN on gfx950 — dataflow pipeline, round 9.
// Round-8 state passed at 16.0 ms with MfmaUtil=0.3%: entirely latency-bound
// on the handoff protocol (15.5 us/step vs ~0.1 us compute).
// This round rewrites ONLY the transport protocol:
//   - per-slice monotonic stamp flags (single writer, relaxed stores)
//     instead of 8-way contended fetch_add accumulation (RMW convoy gone)
//   - lane-parallel fused poll: lane i loads flag (i&15), __all(...) —
//     one load latency observes both fA and fC conditions, per wave,
//     no tid0->syncthreads broadcast barrier
//   - producer: one __syncthreads (vmcnt drain = store fence) + RELAXED
//     stamp store; agent-release cache maintenance removed (all
//     communicated data is already L2-bypassing agent-scope atomic)
// Compute geometry (4 groups x 8 slices x 2 roles, weights in registers)
// is unchanged from the passing round-8 kernel.

typedef __bf16 bf16_t;
typedef __bf16 bf16x8 __attribute__((ext_vector_type(8)));
typedef float  floatx4 __attribute__((ext_vector_type(4)));
typedef unsigned int  u32;
typedef unsigned short u16;
typedef u32 u32x4 __attribute__((ext_vector_type(4)));

#define S_LEN  1024
#define BATCH  64
#define EMBD   256
#define HID    512
#define VOCAB  50000
#define D0     8
#define D1     4
#define NGROUP 4
#define NSLICE 8
#define NFLAGS (NGROUP * 16)   // per group: [0..8)=layer0 slice stamps, [8..16)=layer1
#define RING0_ELEMS ((size_t)D0*BATCH*HID)
#define RING1_ELEMS ((size_t)D1*BATCH*HID)
#define INIT_WORDS ((RING0_ELEMS + RING1_ELEMS)/2 + NFLAGS)

__device__ __attribute__((aligned(16))) bf16_t g_h0ring[RING0_ELEMS];
__device__ __attribute__((aligned(16))) bf16_t g_h1ring[RING1_ELEMS];
__device__ __attribute__((aligned(64))) int g_f2[NFLAGS];

// ---- transport: scoped atomics, agent scope ----
__device__ __forceinline__ void at_store16(u16* p, u16 v) {
  __hip_atomic_store(p, v, __ATOMIC_RELAXED, __HIP_MEMORY_SCOPE_AGENT);
}
__device__ __forceinline__ void at_store32(u32* p, u32 v) {
  __hip_atomic_store(p, v, __ATOMIC_RELAXED, __HIP_MEMORY_SCOPE_AGENT);
}
__device__ __forceinline__ u32 at_load32(const u32* p) {
  return __hip_atomic_load(p, __ATOMIC_RELAXED, __HIP_MEMORY_SCOPE_AGENT);
}
__device__ __forceinline__ int at_loadi(const int* p) {
  return __hip_atomic_load(p, __ATOMIC_RELAXED, __HIP_MEMORY_SCOPE_AGENT);
}
__device__ __forceinline__ void at_storei(int* p, int v) {
  __hip_atomic_store(p, v, __ATOMIC_RELAXED, __HIP_MEMORY_SCOPE_AGENT);
}
__device__ __forceinline__ bf16x8 at_load_frag(const bf16_t* p) {
  const u32* q = (const u32*)p;
  u32x4 w;
  w[0] = at_load32(q + 0);
  w[1] = at_load32(q + 1);
  w[2] = at_load32(q + 2);
  w[3] = at_load32(q + 3);
  return __builtin_bit_cast(bf16x8, w);
}

// Lane-parallel fused wait: lane i polls flag (i&15) of the group line.
// idx<8 -> layer0 stamps vs ta ; idx>=8 -> layer1 stamps vs tc.
// Stamps are monotonic nonneg, so target<=0 means trivially satisfied.
__device__ __forceinline__ void wait_pair(const int* fg, int ta, int tc, int lane) {
  if (ta <= 0 && tc <= 0) return;
  int idx = lane & 15;
  int tgt = (idx < 8) ? ta : tc;
  const int* p = fg + idx;
  while (!__all(at_loadi(p) >= tgt))
    __builtin_amdgcn_s_sleep(1);
}
__device__ __forceinline__ void wait_one(const int* f8, int tgt, int lane) {
  if (tgt <= 0) return;
  const int* p = f8 + (lane & 7);
  while (!__all(at_loadi(p) >= tgt))
    __builtin_amdgcn_s_sleep(1);
}

__device__ __forceinline__ float act_tanh(float x) {
  x = fminf(fmaxf(x, -12.0f), 12.0f);   // NaN-proof: fmaxf(NaN,-12)=-12
  float e = __expf(2.0f * x);
  return 1.0f - 2.0f / (e + 1.0f);
}

// B-fragment from row-major f32 W[K][512]: elem j = (bf16)W[kbase+j][col]
__device__ __forceinline__ bf16x8 load_bfrag(const float* __restrict__ W,
                                             int kbase, int col) {
  bf16x8 v;
#pragma unroll
  for (int j = 0; j < 8; ++j) v[j] = (bf16_t)W[(size_t)(kbase + j) * HID + col];
  return v;
}
// A-fragment: 8 consecutive f32 -> bf16
__device__ __forceinline__ bf16x8 load_afrag(const float* __restrict__ p) {
  bf16x8 v;
#pragma unroll
  for (int j = 0; j < 8; ++j) v[j] = (bf16_t)p[j];
  return v;
}

__global__ __launch_bounds__(256) void k_init() {
  size_t i = (size_t)blockIdx.x * 256 + threadIdx.x;
  size_t r0w = RING0_ELEMS / 2, r1w = RING1_ELEMS / 2;
  if (i < r0w)             at_store32((u32*)g_h0ring + i, 0u);
  else if (i < r0w + r1w)  at_store32((u32*)g_h1ring + (i - r0w), 0u);
  else if (i < INIT_WORDS) at_store32((u32*)g_f2 + (i - r0w - r1w), 0u);
}

__global__ __launch_bounds__(256, 1) void k_rnn(
    const int* __restrict__ x,
    const float* __restrict__ emb,
    const float* __restrict__ Wxh0,
    const float* __restrict__ bxh0, const float* __restrict__ bhh0,
    const float* __restrict__ Whh0,
    const float* __restrict__ Wxh1,
    const float* __restrict__ bxh1, const float* __restrict__ bhh1,
    const float* __restrict__ Whh1) {
  int bid = blockIdx.x;
  int role = bid & 1, g = (bid >> 1) & 3, s = bid >> 3;
  int tid = threadIdx.x;
  int wv = tid >> 6, lane = tid & 63, l15 = lane & 15, quad = lane >> 4;
  int col = s * 64 + wv * 16 + l15;  // output column (B-frag n / C-frag col)
  int arow = g * 16 + l15;           // batch row (A-frag m = lane&15)
  int crow = g * 16 + quad * 4;      // first C-frag row (row = quad*4 + reg)
  int kb = quad * 8;                 // A/B-frag k-base within a 32-chunk
  int* fg = g_f2 + g * 16;           // this group's stamp line (fA[0..8), fC[8..16))

  if (role == 0) {
    // ---- layer 0: h0[t] = tanh(emb[x_t]@Wxh0 + b + h0[t-1]@Whh0) ----
    bf16x8 bw[16], bwx[8];
#pragma unroll
    for (int ks = 0; ks < 16; ++ks) bw[ks]  = load_bfrag(Whh0, ks * 32 + kb, col);
#pragma unroll
    for (int ks = 0; ks < 8;  ++ks) bwx[ks] = load_bfrag(Wxh0, ks * 32 + kb, col);
    float bb = bxh0[col] + bhh0[col];

    int xrow = arow * S_LEN;
    bf16x8 ea[8], en[8];
    {
      int xi0 = x[xrow];
      xi0 = xi0 < 0 ? 0 : (xi0 >= VOCAB ? VOCAB - 1 : xi0);
      const float* ep = emb + (size_t)xi0 * EMBD + kb;
#pragma unroll
      for (int ks = 0; ks < 8; ++ks) ea[ks] = load_afrag(ep + ks * 32);
    }
    int xiB = x[xrow + 1];

    for (int t = 0; t < S_LEN; ++t) {
      if (t + 1 < S_LEN) {
        int xi = xiB < 0 ? 0 : (xiB >= VOCAB ? VOCAB - 1 : xiB);
        const float* ep = emb + (size_t)xi * EMBD + kb;
#pragma unroll
        for (int ks = 0; ks < 8; ++ks) en[ks] = load_afrag(ep + ks * 32);
      }
      int tn = (t + 2 < S_LEN) ? t + 2 : S_LEN - 1;
      int xiC = x[xrow + tn];

      // front GEMM (registers only) overlaps the flag-observation latency
      floatx4 acc = (floatx4){bb, bb, bb, bb};
#pragma unroll
      for (int ks = 0; ks < 8; ++ks)
        acc = __builtin_amdgcn_mfma_f32_16x16x32_bf16(ea[ks], bwx[ks], acc, 0, 0, 0);

      // need: all layer0 slices finished t-1 (h0[t-1] complete) AND
      //       all layer1 slices finished t-D0 (ring slot t%D0 consumed)
      wait_pair(fg, t, t - D0 + 1, lane);

      if (t > 0) {
        const bf16_t* hp = g_h0ring + (size_t)((t - 1) % D0) * BATCH * HID
                         + (size_t)arow * HID + kb;
#pragma unroll
        for (int ks = 0; ks < 16; ++ks) {
          bf16x8 af = at_load_frag(hp + ks * 32);
          acc = __builtin_amdgcn_mfma_f32_16x16x32_bf16(af, bw[ks], acc, 0, 0, 0);
        }
      }
      bf16_t* hw = g_h0ring + (size_t)(t % D0) * BATCH * HID
                 + (size_t)crow * HID + col;
#pragma unroll
      for (int i = 0; i < 4; ++i) {
        bf16_t hv = (bf16_t)act_tanh(acc[i]);
        at_store16((u16*)(hw + i * HID), __builtin_bit_cast(u16, hv));
      }

      __syncthreads(); // drains all waves' atomic stores (vmcnt) pre-stamp
      if (tid == 0) at_storei(&fg[s], t + 1);   // relaxed monotonic stamp
#pragma unroll
      for (int ks = 0; ks < 8; ++ks) ea[ks] = en[ks];
      xiB = xiC;
    }
  } else {
    // ---- layer 1: h1[t] = tanh(h0[t]@Wxh1 + b + h1[t-1]@Whh1) ----
    bf16x8 bwx[16], bwh[16];
#pragma unroll
    for (int ks = 0; ks < 16; ++ks) {
      bwx[ks] = load_bfrag(Wxh1, ks * 32 + kb, col);
      bwh[ks] = load_bfrag(Whh1, ks * 32 + kb, col);
    }
    float bb = bxh1[col] + bhh1[col];

    for (int t = 0; t < S_LEN; ++t) {
      // own-layer prev step (h1[t-1] complete across all slices)
      wait_one(fg + 8, t, lane);

      floatx4 acc = (floatx4){bb, bb, bb, bb};
      if (t > 0) {
        const bf16_t* hp = g_h1ring + (size_t)((t - 1) % D1) * BATCH * HID
                         + (size_t)arow * HID + kb;
#pragma unroll
        for (int ks = 0; ks < 16; ++ks) {
          bf16x8 af = at_load_frag(hp + ks * 32);
          acc = __builtin_amdgcn_mfma_f32_16x16x32_bf16(af, bwh[ks], acc, 0, 0, 0);
        }
      }

      // h0[t] ready (overlapped the h1 GEMM with layer0's production)
      wait_one(fg, t + 1, lane);
      {
        const bf16_t* hp = g_h0ring + (size_t)(t % D0) * BATCH * HID
                         + (size_t)arow * HID + kb;
#pragma unroll
        for (int ks = 0; ks < 16; ++ks) {
          bf16x8 af = at_load_frag(hp + ks * 32);
          acc = __builtin_amdgcn_mfma_f32_16x16x32_bf16(af, bwx[ks], acc, 0, 0, 0);
        }
      }
      bf16_t* hw = g_h1ring + (size_t)(t % D1) * BATCH * HID
                 + (size_t)crow * HID + col;
#pragma unroll
      for (int i = 0; i < 4; ++i) {
        bf16_t hv = (bf16_t)act_tanh(acc[i]);
        at_store16((u16*)(hw + i * HID), __builtin_bit_cast(u16, hv));
      }

      __syncthreads(); // drain stores pre-stamp
      if (tid == 0) at_storei(&fg[8 + s], t + 1);
    }
  }
}

__global__ __launch_bounds__(64) void k_out(const float* __restrict__ fc_w,
                                            const float* __restrict__ fc_b,
                                            float* __restrict__ out) {
  int b = threadIdx.x;
  const bf16_t* hr = g_h1ring + (size_t)((S_LEN - 1) % D1) * BATCH * HID
                   + (size_t)b * HID;
  float acc = fc_b[0];
#pragma unroll 4
  for (int k = 0; k < HID; k += 2) {
    u32 w = at_load32((const u32*)(hr + k));
    bf16_t h0 = __builtin_bit_cast(bf16_t, (u16)(w & 0xffffu));
    bf16_t h1 = __builtin_bit_cast(bf16_t, (u16)(w >> 16));
    acc += (float)h0 * fc_w[k] + (float)h1 * fc_w[k + 1];
  }
  acc = fminf(fmaxf(acc, -30.0f), 30.0f);  // NaN canary: NaN -> sigmoid(-30)
  out[b] = 1.0f / (1.0f + __expf(-acc));
}

extern "C" void kernel_launch(void* const* d_in, const int* in_sizes, int n_in,
                              void* d_out, int out_size, void* d_ws, size_t ws_size,
                              hipStream_t stream) {
  const int*   x    = (const int*)d_in[0];
  const float* emb  = (const float*)d_in[1];
  const float* Wxh0 = (const float*)d_in[2];
  const float* bxh0 = (const float*)d_in[3];
  const float* Whh0 = (const float*)d_in[4];
  const float* bhh0 = (const float*)d_in[5];
  const float* Wxh1 = (const float*)d_in[6];
  const float* bxh1 = (const float*)d_in[7];
  const float* Whh1 = (const float*)d_in[8];
  const float* bhh1 = (const float*)d_in[9];
  const float* fc_w = (const float*)d_in[10];
  const float* fc_b = (const float*)d_in[11];
  (void)d_ws; (void)ws_size; (void)in_sizes; (void)n_in; (void)out_size;

  hipLaunchKernelGGL(k_init, dim3((INIT_WORDS + 255) / 256), dim3(256), 0, stream);
  hipLaunchKernelGGL(k_rnn, dim3(NGROUP * 2 * NSLICE), dim3(256), 0, stream,
                     x, emb, Wxh0, bxh0, bhh0, Whh0, Wxh1, bxh1, bhh1, Whh1);
  hipLaunchKernelGGL(k_out, dim3(1), dim3(64), 0, stream,
                     fc_w, fc_b, (float*)d_out);
}

// Round 2
// 6443.742 us; speedup vs baseline: 2.4896x; 2.4258x over previous
//
#include <hip/hip_runtime.h>
#include <hip/hip_bf16.h>
#include <math.h>

// MultiLayerRNN on gfx950 — dataflow pipeline, round 10.
// r9 post-mortem: stamp protocol rewrite only bought 2.6% -> the 15.2us/step
// floor is NOT the flag protocol. Theory: the ring reads (64 x 4B agent-scope
// __hip_atomic_load per 16-frag GEMM) are compiler-serialized into ~one LLC
// round trip (~600cy) per fragment: role1's 2 GEMMs ~= 32 trips ~= 15-19us.
// Fix: ring data is IMMUTABLE once the stamp is observed (single writer, slot
// reuse D0 steps away) -> no atomicity needed, only L2-bypass freshness +
// issue-after-poll ordering. Replace with inline-asm global_load_dwordx4
// sc0 sc1 (system-scope, L2-bypassing, LLC-coherent), issued in banks of 8
// with ONE s_waitcnt vmcnt(0) + sched_barrier(0) per bank (rule #18).
//   - per-WAVE stamps (8 slices x 4 waves per layer per group): each wave
//     drains its own stores (s_waitcnt vmcnt(0)) and stamps; consumers poll
//     all 32 producer-wave stamps lane-parallel. NO __syncthreads in loop.
//   - k_out rewritten with the same wide coherent loads (was ~100us of
//     serialized scalar atomic loads).
// Compute geometry (4 groups x 8 slices x 2 roles, weights in registers)
// unchanged from the passing r9 kernel.

typedef __bf16 bf16_t;
typedef __bf16 bf16x8 __attribute__((ext_vector_type(8)));
typedef float  floatx4 __attribute__((ext_vector_type(4)));
typedef unsigned int  u32;
typedef unsigned short u16;
typedef u32 u32x4 __attribute__((ext_vector_type(4)));

#define S_LEN  1024
#define BATCH  64
#define EMBD   256
#define HID    512
#define VOCAB  50000
#define D0     8
#define D1     4
#define NGROUP 4
#define NSLICE 8
// per group: [0..32) = layer0 wave stamps (s*4+wv), [32..64) = layer1
#define NFLAGS (NGROUP * 64)
#define RING0_ELEMS ((size_t)D0*BATCH*HID)
#define RING1_ELEMS ((size_t)D1*BATCH*HID)
#define INIT_WORDS ((RING0_ELEMS + RING1_ELEMS)/2 + NFLAGS)

__device__ __attribute__((aligned(16)))  bf16_t g_h0ring[RING0_ELEMS];
__device__ __attribute__((aligned(16)))  bf16_t g_h1ring[RING1_ELEMS];
__device__ __attribute__((aligned(256))) int g_f2[NFLAGS];

// ---- transport primitives ----
__device__ __forceinline__ void at_store16(u16* p, u16 v) {
  __hip_atomic_store(p, v, __ATOMIC_RELAXED, __HIP_MEMORY_SCOPE_AGENT);
}
__device__ __forceinline__ void at_store32(u32* p, u32 v) {
  __hip_atomic_store(p, v, __ATOMIC_RELAXED, __HIP_MEMORY_SCOPE_AGENT);
}
__device__ __forceinline__ int at_loadi(const int* p) {
  return __hip_atomic_load(p, __ATOMIC_RELAXED, __HIP_MEMORY_SCOPE_AGENT);
}
__device__ __forceinline__ void at_storei(int* p, int v) {
  __hip_atomic_store(p, v, __ATOMIC_RELAXED, __HIP_MEMORY_SCOPE_AGENT);
}

// Lane-parallel waits over per-wave stamps.
// wait_fused: lanes 0..31 poll layer0 stamps vs ta, lanes 32..63 poll layer1
// stamps vs tc (stamps are monotonic nonneg -> tgt<=0 auto-satisfied).
__device__ __forceinline__ void wait_fused(const int* fg, int ta, int tc, int lane) {
  if (ta <= 0 && tc <= 0) return;
  const int* p = fg + lane;
  int tgt = (lane < 32) ? ta : tc;
  while (!__all(at_loadi(p) >= tgt)) __builtin_amdgcn_s_sleep(1);
}
__device__ __forceinline__ void wait_set(const int* fs, int tgt, int lane) {
  if (tgt <= 0) return;
  const int* p = fs + (lane & 31);
  while (!__all(at_loadi(p) >= tgt)) __builtin_amdgcn_s_sleep(1);
}

// 16-fragment ring GEMM: K=512 slab read with pipelined L2-bypassing
// dwordx4 loads (2 banks of 8, one waitcnt each), then MFMA chains.
// Safe because slab content is stable once the producer stamp is observed;
// in-order VMEM issue means these loads launch after the poll load completed.
__device__ __forceinline__ floatx4 ring_gemm16(const bf16_t* hp,
                                               const bf16x8* bwf, floatx4 acc) {
  u32x4 rw[8];
#pragma unroll
  for (int ks = 0; ks < 8; ++ks)
    asm volatile("global_load_dwordx4 %0, %1, off offset:%2 sc0 sc1"
                 : "=v"(rw[ks]) : "v"(hp), "i"(ks * 64) : "memory");
  asm volatile("s_waitcnt vmcnt(0)" ::: "memory");
  __builtin_amdgcn_sched_barrier(0);
#pragma unroll
  for (int ks = 0; ks < 8; ++ks)
    acc = __builtin_amdgcn_mfma_f32_16x16x32_bf16(
        __builtin_bit_cast(bf16x8, rw[ks]), bwf[ks], acc, 0, 0, 0);
#pragma unroll
  for (int ks = 0; ks < 8; ++ks)
    asm volatile("global_load_dwordx4 %0, %1, off offset:%2 sc0 sc1"
                 : "=v"(rw[ks]) : "v"(hp), "i"(512 + ks * 64) : "memory");
  asm volatile("s_waitcnt vmcnt(0)" ::: "memory");
  __builtin_amdgcn_sched_barrier(0);
#pragma unroll
  for (int ks = 0; ks < 8; ++ks)
    acc = __builtin_amdgcn_mfma_f32_16x16x32_bf16(
        __builtin_bit_cast(bf16x8, rw[ks]), bwf[ks + 8], acc, 0, 0, 0);
  return acc;
}

__device__ __forceinline__ float act_tanh(float x) {
  x = fminf(fmaxf(x, -12.0f), 12.0f);   // NaN-proof: fmaxf(NaN,-12)=-12
  float e = __expf(2.0f * x);
  return 1.0f - 2.0f / (e + 1.0f);
}

// B-fragment from row-major f32 W[K][512]: elem j = (bf16)W[kbase+j][col]
__device__ __forceinline__ bf16x8 load_bfrag(const float* __restrict__ W,
                                             int kbase, int col) {
  bf16x8 v;
#pragma unroll
  for (int j = 0; j < 8; ++j) v[j] = (bf16_t)W[(size_t)(kbase + j) * HID + col];
  return v;
}
// A-fragment: 8 consecutive f32 -> bf16
__device__ __forceinline__ bf16x8 load_afrag(const float* __restrict__ p) {
  bf16x8 v;
#pragma unroll
  for (int j = 0; j < 8; ++j) v[j] = (bf16_t)p[j];
  return v;
}

__global__ __launch_bounds__(256) void k_init() {
  size_t i = (size_t)blockIdx.x * 256 + threadIdx.x;
  size_t r0w = RING0_ELEMS / 2, r1w = RING1_ELEMS / 2;
  if (i < r0w)             at_store32((u32*)g_h0ring + i, 0u);
  else if (i < r0w + r1w)  at_store32((u32*)g_h1ring + (i - r0w), 0u);
  else if (i < INIT_WORDS) at_store32((u32*)g_f2 + (i - r0w - r1w), 0u);
}

__global__ __launch_bounds__(256, 1) void k_rnn(
    const int* __restrict__ x,
    const float* __restrict__ emb,
    const float* __restrict__ Wxh0,
    const float* __restrict__ bxh0, const float* __restrict__ bhh0,
    const float* __restrict__ Whh0,
    const float* __restrict__ Wxh1,
    const float* __restrict__ bxh1, const float* __restrict__ bhh1,
    const float* __restrict__ Whh1) {
  int bid = blockIdx.x;
  int role = bid & 1, g = (bid >> 1) & 3, s = bid >> 3;
  int tid = threadIdx.x;
  int wv = tid >> 6, lane = tid & 63, l15 = lane & 15, quad = lane >> 4;
  int col = s * 64 + wv * 16 + l15;  // output column (B-frag n / C-frag col)
  int arow = g * 16 + l15;           // batch row (A-frag m = lane&15)
  int crow = g * 16 + quad * 4;      // first C-frag row (row = quad*4 + reg)
  int kb = quad * 8;                 // A/B-frag k-base within a 32-chunk
  int sw = s * 4 + wv;               // this wave's stamp slot
  int* fg = g_f2 + g * 64;           // group flag base: fA[0..32), fC[32..64)

  if (role == 0) {
    // ---- layer 0: h0[t] = tanh(emb[x_t]@Wxh0 + b + h0[t-1]@Whh0) ----
    bf16x8 bw[16], bwx[8];
#pragma unroll
    for (int ks = 0; ks < 16; ++ks) bw[ks]  = load_bfrag(Whh0, ks * 32 + kb, col);
#pragma unroll
    for (int ks = 0; ks < 8;  ++ks) bwx[ks] = load_bfrag(Wxh0, ks * 32 + kb, col);
    float bb = bxh0[col] + bhh0[col];

    int xrow = arow * S_LEN;
    bf16x8 ea[8], en[8];
    {
      int xi0 = x[xrow];
      xi0 = xi0 < 0 ? 0 : (xi0 >= VOCAB ? VOCAB - 1 : xi0);
      const float* ep = emb + (size_t)xi0 * EMBD + kb;
#pragma unroll
      for (int ks = 0; ks < 8; ++ks) ea[ks] = load_afrag(ep + ks * 32);
    }
    int xiB = x[xrow + 1];

    for (int t = 0; t < S_LEN; ++t) {
      if (t + 1 < S_LEN) {
        int xi = xiB < 0 ? 0 : (xiB >= VOCAB ? VOCAB - 1 : xiB);
        const float* ep = emb + (size_t)xi * EMBD + kb;
#pragma unroll
        for (int ks = 0; ks < 8; ++ks) en[ks] = load_afrag(ep + ks * 32);
      }
      int tn = (t + 2 < S_LEN) ? t + 2 : S_LEN - 1;
      int xiC = x[xrow + tn];

      // front GEMM (registers only) overlaps prefetch + flag observation
      floatx4 acc = (floatx4){bb, bb, bb, bb};
#pragma unroll
      for (int ks = 0; ks < 8; ++ks)
        acc = __builtin_amdgcn_mfma_f32_16x16x32_bf16(ea[ks], bwx[ks], acc, 0, 0, 0);

      // all layer0 waves done t-1 AND all layer1 waves done t-D0 (slot free)
      wait_fused(fg, t, t - D0 + 1, lane);

      if (t > 0) {
        const bf16_t* hp = g_h0ring + (size_t)((t - 1) % D0) * BATCH * HID
                         + (size_t)arow * HID + kb;
        acc = ring_gemm16(hp, bw, acc);
      }
      bf16_t* hw = g_h0ring + (size_t)(t % D0) * BATCH * HID
                 + (size_t)crow * HID + col;
#pragma unroll
      for (int i = 0; i < 4; ++i) {
        bf16_t hv = (bf16_t)act_tanh(acc[i]);
        at_store16((u16*)(hw + i * HID), __builtin_bit_cast(u16, hv));
      }

      // per-wave drain (stores acked at coherent point), then stamp
      asm volatile("s_waitcnt vmcnt(0)" ::: "memory");
      if (lane == 0) at_storei(&fg[sw], t + 1);
#pragma unroll
      for (int ks = 0; ks < 8; ++ks) ea[ks] = en[ks];
      xiB = xiC;
    }
  } else {
    // ---- layer 1: h1[t] = tanh(h0[t]@Wxh1 + b + h1[t-1]@Whh1) ----
    bf16x8 bwx[16], bwh[16];
#pragma unroll
    for (int ks = 0; ks < 16; ++ks) {
      bwx[ks] = load_bfrag(Wxh1, ks * 32 + kb, col);
      bwh[ks] = load_bfrag(Whh1, ks * 32 + kb, col);
    }
    float bb = bxh1[col] + bhh1[col];

    for (int t = 0; t < S_LEN; ++t) {
      // own-layer prev step complete (h1[t-1] ready, slot reuse safe)
      wait_set(fg + 32, t, lane);

      floatx4 acc = (floatx4){bb, bb, bb, bb};
      if (t > 0) {
        const bf16_t* hp = g_h1ring + (size_t)((t - 1) % D1) * BATCH * HID
                         + (size_t)arow * HID + kb;
        acc = ring_gemm16(hp, bwh, acc);
      }

      // h0[t] ready (h1 GEMM above overlapped layer0's production)
      wait_set(fg, t + 1, lane);
      {
        const bf16_t* hp = g_h0ring + (size_t)(t % D0) * BATCH * HID
                         + (size_t)arow * HID + kb;
        acc = ring_gemm16(hp, bwx, acc);
      }
      bf16_t* hw = g_h1ring + (size_t)(t % D1) * BATCH * HID
                 + (size_t)crow * HID + col;
#pragma unroll
      for (int i = 0; i < 4; ++i) {
        bf16_t hv = (bf16_t)act_tanh(acc[i]);
        at_store16((u16*)(hw + i * HID), __builtin_bit_cast(u16, hv));
      }

      asm volatile("s_waitcnt vmcnt(0)" ::: "memory");
      if (lane == 0) at_storei(&fg[32 + sw], t + 1);
    }
  }
}

__global__ __launch_bounds__(64) void k_out(const float* __restrict__ fc_w,
                                            const float* __restrict__ fc_b,
                                            float* __restrict__ out) {
  int b = threadIdx.x;
  const bf16_t* hr = g_h1ring + (size_t)((S_LEN - 1) % D1) * BATCH * HID
                   + (size_t)b * HID;
  float acc = fc_b[0];
  for (int c = 0; c < HID; c += 64) {
    u32x4 rw[8];
#pragma unroll
    for (int i = 0; i < 8; ++i)
      asm volatile("global_load_dwordx4 %0, %1, off offset:%2 sc0 sc1"
                   : "=v"(rw[i]) : "v"(hr + c), "i"(i * 16) : "memory");
    asm volatile("s_waitcnt vmcnt(0)" ::: "memory");
    __builtin_amdgcn_sched_barrier(0);
#pragma unroll
    for (int i = 0; i < 8; ++i) {
      bf16x8 h = __builtin_bit_cast(bf16x8, rw[i]);
#pragma unroll
      for (int j = 0; j < 8; ++j)
        acc += (float)h[j] * fc_w[c + i * 8 + j];
    }
  }
  acc = fminf(fmaxf(acc, -30.0f), 30.0f);  // NaN canary: NaN -> sigmoid(-30)
  out[b] = 1.0f / (1.0f + __expf(-acc));
}

extern "C" void kernel_launch(void* const* d_in, const int* in_sizes, int n_in,
                              void* d_out, int out_size, void* d_ws, size_t ws_size,
                              hipStream_t stream) {
  const int*   x    = (const int*)d_in[0];
  const float* emb  = (const float*)d_in[1];
  const float* Wxh0 = (const float*)d_in[2];
  const float* bxh0 = (const float*)d_in[3];
  const float* Whh0 = (const float*)d_in[4];
  const float* bhh0 = (const float*)d_in[5];
  const float* Wxh1 = (const float*)d_in[6];
  const float* bxh1 = (const float*)d_in[7];
  const float* Whh1 = (const float*)d_in[8];
  const float* bhh1 = (const float*)d_in[9];
  const float* fc_w = (const float*)d_in[10];
  const float* fc_b = (const float*)d_in[11];
  (void)d_ws; (void)ws_size; (void)in_sizes; (void)n_in; (void)out_size;

  hipLaunchKernelGGL(k_init, dim3((INIT_WORDS + 255) / 256), dim3(256), 0, stream);
  hipLaunchKernelGGL(k_rnn, dim3(NGROUP * 2 * NSLICE), dim3(256), 0, stream,
                     x, emb, Wxh0, bxh0, bhh0, Whh0, Wxh1, bxh1, bhh1, Whh1);
  hipLaunchKernelGGL(k_out, dim3(1), dim3(64), 0, stream,
                     fc_w, fc_b, (float*)d_out);
}

// Round 5
// 5955.642 us; speedup vs baseline: 2.6937x; 1.0820x over previous
//
#include <hip/hip_runtime.h>
#include <hip/hip_bf16.h>
#include <math.h>

// MultiLayerRNN on gfx950 — dataflow pipeline, round 13.
// r12 FAILED (absmax 0.321): the k_out "simplification" only covered 128 of
// 512 h1 elements (16x16B = 256B of 1024B) — dropped 384 FC terms; the
// magnitude (max-batch ~0.32 post-sigmoid) closes exactly. k_rnn was NOT
// implicated. This round: k_out restored to full coverage (4 banks x 16
// dwordx4 = 1024B); k_rnn byte-identical to r12:
//   - fused single poll for layer1 (fA>=t+1 lanes<32, fC>=t lanes>=32)
//   - ONE load batch per step: all 32 ring fragments issued back-to-back,
//     one s_waitcnt vmcnt(0) + sched_barrier(0), then all MFMAs.
//   - t>0 guards dropped: read slot (t+D-1)%D; step-0 reads k_init zeros.
//   - tight drain: emb prefetch + x-index loads AFTER the stamp.
//   - MFMA chains split into 2 accumulators.
// Geometry (4 groups x 8 slices x 2 roles, weights in registers) unchanged.

typedef __bf16 bf16_t;
typedef __bf16 bf16x8 __attribute__((ext_vector_type(8)));
typedef float  floatx4 __attribute__((ext_vector_type(4)));
typedef unsigned int  u32;
typedef unsigned short u16;
typedef u32 u32x4 __attribute__((ext_vector_type(4)));

#define S_LEN  1024
#define BATCH  64
#define EMBD   256
#define HID    512
#define VOCAB  50000
#define D0     8
#define D1     4
#define NGROUP 4
#define NSLICE 8
// per group: [0..32) = layer0 wave stamps (s*4+wv), [32..64) = layer1
#define NFLAGS (NGROUP * 64)
#define RING0_ELEMS ((size_t)D0*BATCH*HID)
#define RING1_ELEMS ((size_t)D1*BATCH*HID)
#define INIT_WORDS ((RING0_ELEMS + RING1_ELEMS)/2 + NFLAGS)

__device__ __attribute__((aligned(16)))  bf16_t g_h0ring[RING0_ELEMS];
__device__ __attribute__((aligned(16)))  bf16_t g_h1ring[RING1_ELEMS];
__device__ __attribute__((aligned(256))) int g_f2[NFLAGS];

// ---- transport primitives ----
__device__ __forceinline__ void at_store16(u16* p, u16 v) {
  __hip_atomic_store(p, v, __ATOMIC_RELAXED, __HIP_MEMORY_SCOPE_AGENT);
}
__device__ __forceinline__ void at_store32(u32* p, u32 v) {
  __hip_atomic_store(p, v, __ATOMIC_RELAXED, __HIP_MEMORY_SCOPE_AGENT);
}
__device__ __forceinline__ int at_loadi(const int* p) {
  return __hip_atomic_load(p, __ATOMIC_RELAXED, __HIP_MEMORY_SCOPE_AGENT);
}
__device__ __forceinline__ void at_storei(int* p, int v) {
  __hip_atomic_store(p, v, __ATOMIC_RELAXED, __HIP_MEMORY_SCOPE_AGENT);
}

// Lane-parallel fused wait over per-wave stamps: lanes 0..31 poll set A
// (base fg) vs ta, lanes 32..63 poll set C (fg+32) vs tc. Stamps are
// monotonic nonneg -> tgt<=0 lanes auto-satisfy.
__device__ __forceinline__ void wait_fused(const int* fg, int ta, int tc, int lane) {
  if (ta <= 0 && tc <= 0) return;
  const int* p = fg + lane;
  int tgt = (lane < 32) ? ta : tc;
  while (!__all(at_loadi(p) >= tgt)) __builtin_amdgcn_s_sleep(1);
}

__device__ __forceinline__ float act_tanh(float x) {
  x = fminf(fmaxf(x, -12.0f), 12.0f);   // NaN-proof: fmaxf(NaN,-12)=-12
  float e = __expf(2.0f * x);
  return 1.0f - 2.0f / (e + 1.0f);
}

// B-fragment from row-major f32 W[K][512]: elem j = (bf16)W[kbase+j][col]
__device__ __forceinline__ bf16x8 load_bfrag(const float* __restrict__ W,
                                             int kbase, int col) {
  bf16x8 v;
#pragma unroll
  for (int j = 0; j < 8; ++j) v[j] = (bf16_t)W[(size_t)(kbase + j) * HID + col];
  return v;
}
// A-fragment: 8 consecutive f32 -> bf16
__device__ __forceinline__ bf16x8 load_afrag(const float* __restrict__ p) {
  bf16x8 v;
#pragma unroll
  for (int j = 0; j < 8; ++j) v[j] = (bf16_t)p[j];
  return v;
}

__global__ __launch_bounds__(256) void k_init() {
  size_t i = (size_t)blockIdx.x * 256 + threadIdx.x;
  size_t r0w = RING0_ELEMS / 2, r1w = RING1_ELEMS / 2;
  if (i < r0w)             at_store32((u32*)g_h0ring + i, 0u);
  else if (i < r0w + r1w)  at_store32((u32*)g_h1ring + (i - r0w), 0u);
  else if (i < INIT_WORDS) at_store32((u32*)g_f2 + (i - r0w - r1w), 0u);
}

__global__ __launch_bounds__(256, 1) void k_rnn(
    const int* __restrict__ x,
    const float* __restrict__ emb,
    const float* __restrict__ Wxh0,
    const float* __restrict__ bxh0, const float* __restrict__ bhh0,
    const float* __restrict__ Whh0,
    const float* __restrict__ Wxh1,
    const float* __restrict__ bxh1, const float* __restrict__ bhh1,
    const float* __restrict__ Whh1) {
  int bid = blockIdx.x;
  int role = bid & 1, g = (bid >> 1) & 3, s = bid >> 3;
  int tid = threadIdx.x;
  int wv = tid >> 6, lane = tid & 63, l15 = lane & 15, quad = lane >> 4;
  int col = s * 64 + wv * 16 + l15;  // output column (B-frag n / C-frag col)
  int arow = g * 16 + l15;           // batch row (A-frag m = lane&15)
  int crow = g * 16 + quad * 4;      // first C-frag row (row = quad*4 + reg)
  int kb = quad * 8;                 // A/B-frag k-base within a 32-chunk
  int sw = s * 4 + wv;               // this wave's stamp slot
  int* fg = g_f2 + g * 64;           // group flag base: fA[0..32), fC[32..64)

  if (role == 0) {
    // ---- layer 0: h0[t] = tanh(emb[x_t]@Wxh0 + b + h0[t-1]@Whh0) ----
    bf16x8 bw[16], bwx[8];
#pragma unroll
    for (int ks = 0; ks < 16; ++ks) bw[ks]  = load_bfrag(Whh0, ks * 32 + kb, col);
#pragma unroll
    for (int ks = 0; ks < 8;  ++ks) bwx[ks] = load_bfrag(Wxh0, ks * 32 + kb, col);
    float bb = bxh0[col] + bhh0[col];

    int xrow = arow * S_LEN;
    bf16x8 ea[8];
    {
      int xi0 = x[xrow];
      xi0 = xi0 < 0 ? 0 : (xi0 >= VOCAB ? VOCAB - 1 : xi0);
      const float* ep = emb + (size_t)xi0 * EMBD + kb;
#pragma unroll
      for (int ks = 0; ks < 8; ++ks) ea[ks] = load_afrag(ep + ks * 32);
    }
    int xiB = x[xrow + 1];

#pragma unroll 1
    for (int t = 0; t < S_LEN; ++t) {
      // front GEMM (registers only; ea prefetched last iteration)
      floatx4 acc0 = (floatx4){bb, bb, bb, bb};
#pragma unroll
      for (int ks = 0; ks < 8; ++ks)
        acc0 = __builtin_amdgcn_mfma_f32_16x16x32_bf16(ea[ks], bwx[ks], acc0, 0, 0, 0);

      // all layer0 waves done t-1 AND all layer1 waves done t-D0 (slot free)
      wait_fused(fg, t, t - D0 + 1, lane);

      // h0[t-1] slab: 16 fragments, one batch, one wait (t=0 reads zeros)
      const bf16_t* hp = g_h0ring + (size_t)((t + D0 - 1) % D0) * BATCH * HID
                       + (size_t)arow * HID + kb;
      u32x4 rw[16];
#pragma unroll
      for (int ks = 0; ks < 16; ++ks)
        asm volatile("global_load_dwordx4 %0, %1, off offset:%2 sc0 sc1"
                     : "=v"(rw[ks]) : "v"(hp), "i"(ks * 64) : "memory");
      asm volatile("s_waitcnt vmcnt(0)" ::: "memory");
      __builtin_amdgcn_sched_barrier(0);

      floatx4 acc1 = (floatx4){0.f, 0.f, 0.f, 0.f};
#pragma unroll
      for (int ks = 0; ks < 8; ++ks) {
        acc0 = __builtin_amdgcn_mfma_f32_16x16x32_bf16(
            __builtin_bit_cast(bf16x8, rw[2 * ks]),     bw[2 * ks],     acc0, 0, 0, 0);
        acc1 = __builtin_amdgcn_mfma_f32_16x16x32_bf16(
            __builtin_bit_cast(bf16x8, rw[2 * ks + 1]), bw[2 * ks + 1], acc1, 0, 0, 0);
      }

      bf16_t* hw = g_h0ring + (size_t)(t % D0) * BATCH * HID
                 + (size_t)crow * HID + col;
#pragma unroll
      for (int i = 0; i < 4; ++i) {
        bf16_t hv = (bf16_t)act_tanh(acc0[i] + acc1[i]);
        at_store16((u16*)(hw + i * HID), __builtin_bit_cast(u16, hv));
      }

      // tight drain: only the 4 h-stores are outstanding here
      asm volatile("s_waitcnt vmcnt(0)" ::: "memory");
      if (lane == 0) at_storei(&fg[sw], t + 1);

      // post-stamp: prefetch emb for t+1 and the index for t+2
      if (t + 1 < S_LEN) {
        int xi = xiB < 0 ? 0 : (xiB >= VOCAB ? VOCAB - 1 : xiB);
        const float* ep = emb + (size_t)xi * EMBD + kb;
#pragma unroll
        for (int ks = 0; ks < 8; ++ks) ea[ks] = load_afrag(ep + ks * 32);
        int tn = (t + 2 < S_LEN) ? t + 2 : S_LEN - 1;
        xiB = x[xrow + tn];
      }
    }
  } else {
    // ---- layer 1: h1[t] = tanh(h0[t]@Wxh1 + b + h1[t-1]@Whh1) ----
    bf16x8 bwx[16], bwh[16];
#pragma unroll
    for (int ks = 0; ks < 16; ++ks) {
      bwx[ks] = load_bfrag(Wxh1, ks * 32 + kb, col);
      bwh[ks] = load_bfrag(Whh1, ks * 32 + kb, col);
    }
    float bb = bxh1[col] + bhh1[col];

#pragma unroll 1
    for (int t = 0; t < S_LEN; ++t) {
      // ONE fused poll: h0[t] ready (fA>=t+1) AND h1[t-1] ready (fC>=t)
      wait_fused(fg, t + 1, t, lane);

      const bf16_t* hp0 = g_h0ring + (size_t)(t % D0) * BATCH * HID
                        + (size_t)arow * HID + kb;
      const bf16_t* hp1 = g_h1ring + (size_t)((t + D1 - 1) % D1) * BATCH * HID
                        + (size_t)arow * HID + kb;
      u32x4 rw0[16], rw1[16];
#pragma unroll
      for (int ks = 0; ks < 16; ++ks)
        asm volatile("global_load_dwordx4 %0, %1, off offset:%2 sc0 sc1"
                     : "=v"(rw0[ks]) : "v"(hp0), "i"(ks * 64) : "memory");
#pragma unroll
      for (int ks = 0; ks < 16; ++ks)
        asm volatile("global_load_dwordx4 %0, %1, off offset:%2 sc0 sc1"
                     : "=v"(rw1[ks]) : "v"(hp1), "i"(ks * 64) : "memory");
      asm volatile("s_waitcnt vmcnt(0)" ::: "memory");
      __builtin_amdgcn_sched_barrier(0);

      floatx4 acc0 = (floatx4){bb, bb, bb, bb};
      floatx4 acc1 = (floatx4){0.f, 0.f, 0.f, 0.f};
#pragma unroll
      for (int ks = 0; ks < 16; ++ks) {
        acc0 = __builtin_amdgcn_mfma_f32_16x16x32_bf16(
            __builtin_bit_cast(bf16x8, rw0[ks]), bwx[ks], acc0, 0, 0, 0);
        acc1 = __builtin_amdgcn_mfma_f32_16x16x32_bf16(
            __builtin_bit_cast(bf16x8, rw1[ks]), bwh[ks], acc1, 0, 0, 0);
      }

      bf16_t* hw = g_h1ring + (size_t)(t % D1) * BATCH * HID
                 + (size_t)crow * HID + col;
#pragma unroll
      for (int i = 0; i < 4; ++i) {
        bf16_t hv = (bf16_t)act_tanh(acc0[i] + acc1[i]);
        at_store16((u16*)(hw + i * HID), __builtin_bit_cast(u16, hv));
      }

      asm volatile("s_waitcnt vmcnt(0)" ::: "memory");
      if (lane == 0) at_storei(&fg[32 + sw], t + 1);
    }
  }
}

__global__ __launch_bounds__(64) void k_out(const float* __restrict__ fc_w,
                                            const float* __restrict__ fc_b,
                                            float* __restrict__ out) {
  int b = threadIdx.x;
  const bf16_t* hr = g_h1ring + (size_t)((S_LEN - 1) % D1) * BATCH * HID
                   + (size_t)b * HID;
  float acc = fc_b[0];
  // Full 512-element coverage: 4 banks x 16 x 16B = 1024 bytes. (r12 bug:
  // only 256B were read — 384 FC terms dropped -> absmax 0.321.)
#pragma unroll 1
  for (int c = 0; c < HID; c += 128) {
    u32x4 rw[16];
#pragma unroll
    for (int i = 0; i < 16; ++i)
      asm volatile("global_load_dwordx4 %0, %1, off offset:%2 sc0 sc1"
                   : "=v"(rw[i]) : "v"(hr + c), "i"(i * 16) : "memory");
    asm volatile("s_waitcnt vmcnt(0)" ::: "memory");
    __builtin_amdgcn_sched_barrier(0);
#pragma unroll
    for (int i = 0; i < 16; ++i) {
      bf16x8 h = __builtin_bit_cast(bf16x8, rw[i]);
#pragma unroll
      for (int j = 0; j < 8; ++j)
        acc += (float)h[j] * fc_w[c + i * 8 + j];
    }
  }
  acc = fminf(fmaxf(acc, -30.0f), 30.0f);  // NaN canary: NaN -> sigmoid(-30)
  out[b] = 1.0f / (1.0f + __expf(-acc));
}

extern "C" void kernel_launch(void* const* d_in, const int* in_sizes, int n_in,
                              void* d_out, int out_size, void* d_ws, size_t ws_size,
                              hipStream_t stream) {
  const int*   x    = (const int*)d_in[0];
  const float* emb  = (const float*)d_in[1];
  const float* Wxh0 = (const float*)d_in[2];
  const float* bxh0 = (const float*)d_in[3];
  const float* Whh0 = (const float*)d_in[4];
  const float* bhh0 = (const float*)d_in[5];
  const float* Wxh1 = (const float*)d_in[6];
  const float* bxh1 = (const float*)d_in[7];
  const float* Whh1 = (const float*)d_in[8];
  const float* bhh1 = (const float*)d_in[9];
  const float* fc_w = (const float*)d_in[10];
  const float* fc_b = (const float*)d_in[11];
  (void)d_ws; (void)ws_size; (void)in_sizes; (void)n_in; (void)out_size;

  hipLaunchKernelGGL(k_init, dim3((INIT_WORDS + 255) / 256), dim3(256), 0, stream);
  hipLaunchKernelGGL(k_rnn, dim3(NGROUP * 2 * NSLICE), dim3(256), 0, stream,
                     x, emb, Wxh0, bxh0, bhh0, Whh0, Wxh1, bxh1, bhh1, Whh1);
  hipLaunchKernelGGL(k_out, dim3(1), dim3(64), 0, stream,
                     fc_w, fc_b, (float*)d_out);
}